// Round 1
// 259.297 us; speedup vs baseline: 1.0416x; 1.0416x over previous
//
#include <hip/hip_runtime.h>

#define NNODES 100000
#define NEDGES 3200000
#define ETOT   (NEDGES + NNODES)
#define NEG_SLOPE 0.2f

#define NPB 64                               // nodes per bucket (dst >> 6)
#define NBUCK ((NNODES + NPB - 1) / NPB)     // 1563 buckets
#define NCHUNK 256                           // edge chunks
#define CHUNK_E ((ETOT + NCHUNK - 1) / NCHUNK)  // 12891 edges/chunk
#define M2 (NBUCK * NCHUNK)                  // 400128 (chunk-scan length)
#define NSB2 ((M2 + 511) / 512)              // 782

// bf16 storage via raw ushort — no hip_fp16.h / hip_bf16.h dependency.
__device__ __forceinline__ unsigned short f2bf(float f) {
    unsigned u = __float_as_uint(f);
    u += 0x7FFFu + ((u >> 16) & 1u);         // round-to-nearest-even
    return (unsigned short)(u >> 16);
}
__device__ __forceinline__ float bf2f(unsigned short h) {
    return __uint_as_float(((unsigned)h) << 16);
}

// edge e in [0, NEDGES): src = ei[e], dst = ei[NEDGES+e]
// edge e in [NEDGES, ETOT): self-loop, src = dst = e - NEDGES
__device__ __forceinline__ void edge_sd(int e, const int* __restrict__ ei, int& s, int& d) {
    if (e < NEDGES) { s = ei[e]; d = ei[NEDGES + e]; }
    else            { s = e - NEDGES; d = s; }
}

__device__ __forceinline__ float lrelu(float v) {
    return v > 0.0f ? v : NEG_SLOPE * v;
}

// ---------------- deterministic chunked bucket sort ----------------
// Round-18 change: chunk_hist/chunk_scatter launched with 1024 threads (was 256).

__global__ void chunk_hist(const int* __restrict__ ei, int* __restrict__ H) {
    __shared__ int h[NBUCK];
    int c = blockIdx.x;
    for (int i = threadIdx.x; i < NBUCK; i += blockDim.x) h[i] = 0;
    __syncthreads();
    int lo = c * CHUNK_E, hi = lo + CHUNK_E; if (hi > ETOT) hi = ETOT;
    for (int e = lo + threadIdx.x; e < hi; e += blockDim.x) {
        int d = (e < NEDGES) ? ei[NEDGES + e] : (e - NEDGES);
        atomicAdd(&h[d >> 6], 1);
    }
    __syncthreads();
    for (int i = threadIdx.x; i < NBUCK; i += blockDim.x) H[c * NBUCK + i] = h[i];
}

// 3-phase exclusive scan of H in bucket-major order.
// Linear index i = b*NCHUNK + c (NCHUNK=256: b = i>>8, c = i&255); value = H[c*NBUCK+b].
__global__ void cscan_local(const int* __restrict__ H, int* __restrict__ off,
                            int* __restrict__ bsum2) {
    __shared__ int arr[512];
    int blk = blockIdx.x, t = threadIdx.x;
    int i = blk * 512 + t;
    int v = (i < M2) ? H[(i & (NCHUNK - 1)) * NBUCK + (i >> 8)] : 0;
    arr[t] = v;
    __syncthreads();
    for (int o = 1; o < 512; o <<= 1) {
        int u = (t >= o) ? arr[t - o] : 0;
        __syncthreads();
        arr[t] += u;
        __syncthreads();
    }
    if (i < M2) off[i] = arr[t] - v;
    if (t == 511) bsum2[blk] = arr[t];
}

__global__ void cscan_bsum(const int* __restrict__ bsum2, int* __restrict__ boff2) {
    __shared__ int arr[1024];
    int t = threadIdx.x;
    int v = (t < NSB2) ? bsum2[t] : 0;
    arr[t] = v;
    __syncthreads();
    for (int o = 1; o < 1024; o <<= 1) {
        int u = (t >= o) ? arr[t - o] : 0;
        __syncthreads();
        arr[t] += u;
        __syncthreads();
    }
    if (t < NSB2) boff2[t] = arr[t] - v;
}

__global__ void cscan_add(int* __restrict__ off, const int* __restrict__ boff2) {
    int i = blockIdx.x * 512 + threadIdx.x;
    if (i < M2) off[i] += boff2[blockIdx.x];
}

__global__ void chunk_scatter(const int* __restrict__ ei, const int* __restrict__ off,
                              int* __restrict__ pairs) {
    __shared__ int cur[NBUCK];
    int c = blockIdx.x;
    for (int b = threadIdx.x; b < NBUCK; b += blockDim.x)
        cur[b] = off[b * NCHUNK + c];
    __syncthreads();
    int lo = c * CHUNK_E, hi = lo + CHUNK_E; if (hi > ETOT) hi = ETOT;
    for (int e = lo + threadIdx.x; e < hi; e += blockDim.x) {
        int s, d; edge_sd(e, ei, s, d);
        int slot = atomicAdd(&cur[d >> 6], 1);
        pairs[slot] = ((d & 63) << 17) | s;   // src < 2^17
    }
}

__global__ void fine_sort2(const int* __restrict__ off, const int* __restrict__ pairs,
                           int* __restrict__ row_start, int* __restrict__ csr_src) {
    __shared__ int arr[NPB];
    __shared__ int cur[NPB];
    int b = blockIdx.x;
    int t = threadIdx.x;
    int base = off[b * NCHUNK];
    int bend = (b == NBUCK - 1) ? ETOT : off[(b + 1) * NCHUNK];
    if (t < NPB) arr[t] = 0;
    __syncthreads();
    for (int i = base + t; i < bend; i += blockDim.x)
        atomicAdd(&arr[pairs[i] >> 17], 1);
    __syncthreads();
    int v = (t < NPB) ? arr[t] : 0;
    __syncthreads();
    for (int o = 1; o < NPB; o <<= 1) {           // inclusive scan over 64 counts
        int u = (t < NPB && t >= o) ? arr[t - o] : 0;
        __syncthreads();
        if (t < NPB) arr[t] += u;
        __syncthreads();
    }
    if (t < NPB) {
        int node = b * NPB + t;
        int start = base + arr[t] - v;            // exclusive prefix
        cur[t] = start;
        if (node < NNODES) row_start[node] = start;
    }
    if (b == NBUCK - 1 && t == 0) row_start[NNODES] = ETOT;
    __syncthreads();
    for (int i = base + t; i < bend; i += blockDim.x) {
        int p = pairs[i];
        int slot = atomicAdd(&cur[p >> 17], 1);
        csr_src[slot] = p & 0x1FFFF;
    }
}

// ---------------- attention-vector precompute (proven) ----------------
// cvec layout: [0,1]=c1s  [2,3]=c1d  [4..19]=c2s  [20..35]=c2d
__global__ void prep(const float* __restrict__ W1, const float* __restrict__ as1,
                     const float* __restrict__ ad1, const float* __restrict__ W2,
                     const float* __restrict__ as2, const float* __restrict__ ad2,
                     float* __restrict__ cvec) {
    int t = threadIdx.x;
    if (t < 2) {
        float s = 0.f, d = 0.f;
        for (int f = 0; f < 16; ++f) { s += W1[t * 16 + f] * as1[f]; d += W1[t * 16 + f] * ad1[f]; }
        cvec[t] = s; cvec[2 + t] = d;
    }
    if (t < 16) {
        float s = 0.f, d = 0.f;
        for (int f = 0; f < 64; ++f) { s += W2[t * 64 + f] * as2[f]; d += W2[t * 64 + f] * ad2[f]; }
        cvec[4 + t] = s; cvec[20 + t] = d;
    }
}

__global__ void alpha1(const float* __restrict__ x, const float* __restrict__ cvec,
                       float* __restrict__ as_, float* __restrict__ ad_) {
    int n = blockIdx.x * blockDim.x + threadIdx.x;
    if (n >= NNODES) return;
    float x0 = x[2 * n], x1 = x[2 * n + 1];
    as_[n] = x0 * cvec[0] + x1 * cvec[1];
    ad_[n] = x0 * cvec[2] + x1 * cvec[3];
}

// alpha2 reads the bf16 g table.
__global__ void alpha2(const unsigned short* __restrict__ g, const float* __restrict__ cvec,
                       float* __restrict__ as_, float* __restrict__ ad_) {
    int n = blockIdx.x * blockDim.x + threadIdx.x;
    if (n >= NNODES) return;
    float s = 0.f, d = 0.f;
#pragma unroll
    for (int k = 0; k < 16; ++k) {
        float gv = bf2f(g[n * 16 + k]);
        s += gv * cvec[4 + k];
        d += gv * cvec[20 + k];
    }
    as_[n] = s; ad_[n] = d;
}

// ---------------- layer 1: aggregate x (2 feats), @W1 in epilogue -------------
// Round-19 change: LDS-tree + 6 __syncthreads replaced by in-register
// __shfl_xor butterfly. Per-node fixed cost was the bottleneck (barriers
// couple 4 degree-skewed waves; lane<16 serial LDS reduce). Zero LDS, zero
// barriers; waves retire independently.
__global__ void agg_l1(const int* __restrict__ row_start, const int* __restrict__ csr_src,
                       const float* __restrict__ as_, const float* __restrict__ ad_,
                       const float* __restrict__ x, const float* __restrict__ W1,
                       const float* __restrict__ b1, unsigned short* __restrict__ g) {
    int wave = threadIdx.x >> 6, lane = threadIdx.x & 63;
    int node = blockIdx.x * 4 + wave;          // always < NNODES (exact grid)
    int base = row_start[node], end = row_start[node + 1];
    float adv = ad_[node];
    float a0 = 0.f, a1 = 0.f, ss = 0.f;
    const float2* x2 = (const float2*)x;
    for (int i = base + lane; i < end; i += 64) {
        int sj = csr_src[i];
        float w = __expf(lrelu(as_[sj] + adv));
        float2 xv = x2[sj];
        ss += w;
        a0 += w * xv.x;
        a1 += w * xv.y;
    }
#pragma unroll
    for (int m = 32; m >= 1; m >>= 1) {        // full 64-lane butterfly
        a0 += __shfl_xor(a0, m);
        a1 += __shfl_xor(a1, m);
        ss += __shfl_xor(ss, m);
    }
    if (lane < 16) {
        float v = (a0 * W1[lane] + a1 * W1[16 + lane]) / ss + b1[lane];
        g[node * 16 + lane] = f2bf(v > 0.f ? v : 0.f);
    }
}

// ---------------- layer 2: aggregate bf16 g, @W2 in epilogue ------------------
// 16 groups x 4 lanes; each lane loads a ushort4 (8B) of the 32B row -> 16 rows
// in flight. Round-19: reduction over the 16 groups via __shfl_xor (masks
// 4..32, quad bits q=lane&3 preserved); feature-k total = a[k&3] shuffled
// from lane (k>>2). One division per node (was 16). Zero LDS, zero barriers.
__global__ void agg_l2(const int* __restrict__ row_start, const int* __restrict__ csr_src,
                       const float* __restrict__ as_, const float* __restrict__ ad_,
                       const unsigned short* __restrict__ g, const float* __restrict__ W2,
                       const float* __restrict__ b2, float* __restrict__ out) {
    int wave = threadIdx.x >> 6, lane = threadIdx.x & 63;
    int grp = lane >> 2;              // 0..15: edge group
    int q   = lane & 3;               // 0..3:  feature quad (features q*4..q*4+3)
    int node = blockIdx.x * 4 + wave; // always < NNODES (exact grid)
    int base = row_start[node], end = row_start[node + 1];
    float adv = ad_[node];
    float a0 = 0.f, a1 = 0.f, a2 = 0.f, a3 = 0.f, ss = 0.f;
    for (int i = base + grp; i < end; i += 16) {
        int sj = csr_src[i];                       // uniform within 4-lane group
        float w = __expf(lrelu(as_[sj] + adv));
        ss += w;
        const ushort4* gp = (const ushort4*)(g + sj * 16);  // row 32B-aligned
        ushort4 hv = gp[q];                        // 8B per lane, 32B per group
        a0 += w * bf2f(hv.x);
        a1 += w * bf2f(hv.y);
        a2 += w * bf2f(hv.z);
        a3 += w * bf2f(hv.w);
    }
    // Butterfly over group bits (masks 4,8,16,32): lane l ends with the total
    // over all 16 groups for its quad q = l&3. ss identical across lanes.
    float aq[4] = {a0, a1, a2, a3};
#pragma unroll
    for (int m = 4; m <= 32; m <<= 1) {
        aq[0] += __shfl_xor(aq[0], m);
        aq[1] += __shfl_xor(aq[1], m);
        aq[2] += __shfl_xor(aq[2], m);
        aq[3] += __shfl_xor(aq[3], m);
        ss    += __shfl_xor(ss, m);
    }
    // Feature k (0..15) total lives in a[k&3] of lane (k>>2): broadcast + matvec.
    float o = 0.f;
#pragma unroll
    for (int k = 0; k < 16; ++k) {
        float rk = __shfl(aq[k & 3], k >> 2);      // static index, uniform lane
        o += rk * W2[k * 64 + lane];               // coalesced W2 column
    }
    o = o / ss + b2[lane];                         // single normalize per node
    out[(size_t)node * 64 + lane] = o > 0.f ? o : 0.f;
}

extern "C" void kernel_launch(void* const* d_in, const int* in_sizes, int n_in,
                              void* d_out, int out_size, void* d_ws, size_t ws_size,
                              hipStream_t stream) {
    const float* x     = (const float*)d_in[0];
    const int*   ei    = (const int*)  d_in[1];
    const float* W1    = (const float*)d_in[2];
    const float* as1w  = (const float*)d_in[3];
    const float* ad1w  = (const float*)d_in[4];
    const float* b1    = (const float*)d_in[5];
    const float* W2    = (const float*)d_in[6];
    const float* as2w  = (const float*)d_in[7];
    const float* ad2w  = (const float*)d_in[8];
    const float* b2    = (const float*)d_in[9];
    float* out = (float*)d_out;

    // ws layout (4-byte elems, ~36 MB; 40.4 MB proven available):
    //   row_start[N+4] | csr_src[ETOT] | g[N*16 bf16, in former float slot] |
    //   asb[N] | adb[N] | cvec[64] | pairs[ETOT] | H[M2] | off[M2] |
    //   bsum2[1024] | boff2[1024]
    int* row_start = (int*)d_ws;
    int* csr_src   = row_start + (NNODES + 4);
    float* gslot   = (float*)(csr_src + ETOT);   // N*16 floats reserved
    unsigned short* gbuf = (unsigned short*)gslot;  // N*16 bf16 used
    float* asb     = gslot + (size_t)NNODES * 16;
    float* adb     = asb + NNODES;
    float* cvec    = adb + NNODES;               // 36 floats used
    int* pairs     = (int*)(cvec + 64);          // ETOT
    int* H         = pairs + ETOT;               // M2
    int* off       = H + M2;                     // M2
    int* bsum2     = off + M2;                   // 1024
    int* boff2     = bsum2 + 1024;               // 1024

    const int B = 256;
    const int NB = (NNODES + B - 1) / B;

    // ---- CSR build: deterministic chunked bucket sort ----
    chunk_hist<<<NCHUNK, 1024, 0, stream>>>(ei, H);
    cscan_local<<<NSB2, 512, 0, stream>>>(H, off, bsum2);
    cscan_bsum<<<1, 1024, 0, stream>>>(bsum2, boff2);
    cscan_add<<<NSB2, 512, 0, stream>>>(off, boff2);
    chunk_scatter<<<NCHUNK, 1024, 0, stream>>>(ei, off, pairs);
    fine_sort2<<<NBUCK, B, 0, stream>>>(off, pairs, row_start, csr_src);

    // ---- attention precompute ----
    prep<<<1, 64, 0, stream>>>(W1, as1w, ad1w, W2, as2w, ad2w, cvec);

    // ---- Layer 1: alphas from x, aggregate x, W1 in epilogue (g stored bf16) ----
    alpha1<<<NB, B, 0, stream>>>(x, cvec, asb, adb);
    agg_l1<<<NNODES / 4, B, 0, stream>>>(row_start, csr_src, asb, adb, x, W1, b1, gbuf);

    // ---- Layer 2: alphas from bf16 g, aggregate bf16 g, W2 in epilogue ----
    alpha2<<<NB, B, 0, stream>>>(gbuf, cvec, asb, adb);
    agg_l2<<<NNODES / 4, B, 0, stream>>>(row_start, csr_src, asb, adb, gbuf, W2, b2, out);
}